// Round 5
// baseline (83.679 us; speedup 1.0000x reference)
//
#include <hip/hip_runtime.h>
#include <hip/hip_bf16.h>
#include <cstdint>
#include <cstddef>

#define PI_F 3.14159265358979323846f
#define TWO_PI_F 6.28318530717958647692f

typedef __bf16 bf16x8 __attribute__((ext_vector_type(8)));
typedef __bf16 bf16x4 __attribute__((ext_vector_type(4)));
typedef float  f32x4  __attribute__((ext_vector_type(4)));

__device__ __forceinline__ __bf16 to_bf16(float f) { return (__bf16)f; }

// global -> LDS async copy, 16B per lane; LDS dest is wave-uniform base + lane*16
#define GLD_LDS16(gsrc, ldst)                                            \
  __builtin_amdgcn_global_load_lds(                                      \
      (const __attribute__((address_space(1))) void*)(gsrc),             \
      (__attribute__((address_space(3))) void*)(ldst), 16, 0, 0)

// ---------------------------------------------------------------------------
// Kernel P: per-(layer,pair) beamsplitter params -> ws table.
// ---------------------------------------------------------------------------
__global__ __launch_bounds__(256) void olk_params(
    const float* __restrict__ theta, const float* __restrict__ phi,
    float4* __restrict__ t4, float2* __restrict__ t2) {
  int idx = blockIdx.x * 256 + threadIdx.x;  // 256*128 = 32768 total
  float t = fmodf(theta[idx], PI_F);
  float p = phi[idx];
  if (t > 0.5f * PI_F) { t = PI_F - t; p += PI_F; }
  p = fmodf(p, TWO_PI_F);
  float c  = cosf(t), s  = sinf(t);
  float cp = cosf(p), sp = sinf(p);
  t4[idx] = make_float4(cp * c, sp * c, cp * s, sp * s);
  t2[idx] = make_float2(c, s);
}

// ---------------------------------------------------------------------------
// Build kernel: V = e_r^T, then V <- V * T_l for l = 255..0.
// Output written in MFMA fragment order (see olk_mm).
// ---------------------------------------------------------------------------
struct P8 {
  float4 qa[8];
  float4 qb[8];
  float4 cc[8];
};

template<bool TBL>
__device__ __forceinline__ void loadP8(P8& P, int lb, int lane,
    const float4* __restrict__ t4, const float2* __restrict__ t2,
    const float* __restrict__ theta, const float* __restrict__ phi) {
  if (TBL) {
#pragma unroll
    for (int k = 0; k < 8; ++k) {
      int idx = (lb + k) * 128 + 2 * lane;
      P.qa[k] = t4[idx];
      P.qb[k] = t4[idx + 1];
      P.cc[k] = *(const float4*)&t2[idx];
    }
  } else {
#pragma unroll
    for (int k = 0; k < 8; ++k) {
      int idx = (lb + k) * 128 + 2 * lane;
      float2 th = *(const float2*)&theta[idx];
      float2 ph = *(const float2*)&phi[idx];
      float ta = fmodf(th.x, PI_F), pa = ph.x;
      if (ta > 0.5f * PI_F) { ta = PI_F - ta; pa += PI_F; }
      pa = fmodf(pa, TWO_PI_F);
      float tb = fmodf(th.y, PI_F), pb = ph.y;
      if (tb > 0.5f * PI_F) { tb = PI_F - tb; pb += PI_F; }
      pb = fmodf(pb, TWO_PI_F);
      float ca = cosf(ta), sa = sinf(ta), cpa = cosf(pa), spa = sinf(pa);
      float cb = cosf(tb), sb = sinf(tb), cpb = cosf(pb), spb = sinf(pb);
      P.qa[k] = make_float4(cpa * ca, spa * ca, cpa * sa, spa * sa);
      P.qb[k] = make_float4(cpb * cb, spb * cb, cpb * sb, spb * sb);
      P.cc[k] = make_float4(ca, sa, cb, sb);
    }
  }
}

__device__ __forceinline__ void layer_step(bool odd, int lane,
    float4 qa, float4 qb, float4 cc,
    float& vre0, float& vim0, float& vre1, float& vim1,
    float& vre2, float& vim2, float& vre3, float& vim3) {
  if (!odd) {
    float nr0 = qa.x * vre0 - qa.y * vim0 + qa.z * vre1 - qa.w * vim1;
    float ni0 = qa.x * vim0 + qa.y * vre0 + qa.z * vim1 + qa.w * vre1;
    float nr1 = cc.x * vre1 - cc.y * vre0;
    float ni1 = cc.x * vim1 - cc.y * vim0;
    float nr2 = qb.x * vre2 - qb.y * vim2 + qb.z * vre3 - qb.w * vim3;
    float ni2 = qb.x * vim2 + qb.y * vre2 + qb.z * vim3 + qb.w * vre3;
    float nr3 = cc.z * vre3 - cc.w * vre2;
    float ni3 = cc.z * vim3 - cc.w * vim2;
    vre0 = nr0; vim0 = ni0; vre1 = nr1; vim1 = ni1;
    vre2 = nr2; vim2 = ni2; vre3 = nr3; vim3 = ni3;
  } else {
    int nxt = (lane + 1) & 63, prv = (lane + 63) & 63;
    float xre = __shfl(vre0, nxt, 64);
    float xim = __shfl(vim0, nxt, 64);
    float pre = __shfl(vre3, prv, 64);
    float pim = __shfl(vim3, prv, 64);
    float cp  = __shfl(cc.z, prv, 64);
    float sp  = __shfl(cc.w, prv, 64);
    float nr1 = qa.x * vre1 - qa.y * vim1 + qa.z * vre2 - qa.w * vim2;
    float ni1 = qa.x * vim1 + qa.y * vre1 + qa.z * vim2 + qa.w * vre2;
    float nr2 = cc.x * vre2 - cc.y * vre1;
    float ni2 = cc.x * vim2 - cc.y * vim1;
    float nr3 = qb.x * vre3 - qb.y * vim3 + qb.z * xre - qb.w * xim;
    float ni3 = qb.x * vim3 + qb.y * vre3 + qb.z * xim + qb.w * xre;
    float nr0 = cp * vre0 - sp * pre;
    float ni0 = cp * vim0 - sp * pim;
    vre0 = nr0; vim0 = ni0; vre1 = nr1; vim1 = ni1;
    vre2 = nr2; vim2 = ni2; vre3 = nr3; vim3 = ni3;
  }
}

template<bool TBL>
__global__ __launch_bounds__(256) void olk_build(
    const float* __restrict__ theta, const float* __restrict__ phi,
    const float* __restrict__ outph,
    const float4* __restrict__ t4, const float2* __restrict__ t2,
    __bf16* __restrict__ Tb2) {
  int lane = threadIdx.x & 63;
  int r = blockIdx.x * 4 + (threadIdx.x >> 6);
  int c0 = lane * 4;
  float vre0 = (c0 + 0 == r) ? 1.f : 0.f, vim0 = 0.f;
  float vre1 = (c0 + 1 == r) ? 1.f : 0.f, vim1 = 0.f;
  float vre2 = (c0 + 2 == r) ? 1.f : 0.f, vim2 = 0.f;
  float vre3 = (c0 + 3 == r) ? 1.f : 0.f, vim3 = 0.f;

  P8 A, B;
  loadP8<TBL>(A, 31 * 8, lane, t4, t2, theta, phi);
  for (int it = 0; it < 16; ++it) {
    int bA = 31 - 2 * it;
    int bB = bA - 1;
    loadP8<TBL>(B, bB * 8, lane, t4, t2, theta, phi);
#pragma unroll
    for (int k = 7; k >= 0; --k)
      layer_step((k & 1) != 0, lane, A.qa[k], A.qb[k], A.cc[k],
                 vre0, vim0, vre1, vim1, vre2, vim2, vre3, vim3);
    if (it < 15)
      loadP8<TBL>(A, (bB - 1) * 8, lane, t4, t2, theta, phi);
#pragma unroll
    for (int k = 7; k >= 0; --k)
      layer_step((k & 1) != 0, lane, B.qa[k], B.qb[k], B.cc[k],
                 vre0, vim0, vre1, vim1, vre2, vim2, vre3, vim3);
  }

  float oph = outph[r];
  float co = cosf(oph), so = sinf(oph);
  bf16x4 o;
  o[0] = to_bf16(co * vre0 - so * vim0);
  o[1] = to_bf16(co * vre1 - so * vim1);
  o[2] = to_bf16(co * vre2 - so * vim2);
  o[3] = to_bf16(co * vre3 - so * vim3);

  // Fragment-ordered store: B-frag (8 bf16) for (row, ks, lg) is contiguous
  // 16B at r*256 + ks*32 + lg*8.
  int ks = lane >> 3, sub = lane & 7;
  int pos = ks * 32 + (sub & 3) * 8 + (sub >> 2) * 4;
  *(bf16x4*)(Tb2 + r * 256 + pos) = o;
}

// ---------------------------------------------------------------------------
// Matmul: out[131072][64] = x[131072][256] @ T[64][256]^T, bf16 MFMA 16x16x32.
// R4 structure (B in LDS staged once; full-N per wave; no in-loop barriers)
// PLUS the MLP fix: the 16 x-loads per tile are pinned as one burst with
// sched_barrier(0) fences (the compiler otherwise sinks loads to uses —
// VGPR_Count=32 in R2/R4 proved depth~4 serialization => 2.5 TB/s cap), and
// launch_bounds(256,3) gives the allocator ~170 VGPRs so it never needs the
// serializing schedule. Cross-tile depth-1 pipeline: cvt(t) frees load regs,
// issue loads(t+1), then MFMA(t)+stores(t) run under loads(t+1) latency.
// ---------------------------------------------------------------------------
__global__ __launch_bounds__(256, 3) void olk_mm(
    const float* __restrict__ x, const __bf16* __restrict__ Tb2,
    float* __restrict__ out) {
  __shared__ __bf16 Bl[32 * 512];   // 32 frag-sets x 64 lanes x 8 bf16 = 32KB
  int tid = threadIdx.x, lane = tid & 63, w = tid >> 6;
  int l15 = lane & 15, lg = lane >> 4;

  // Stage B fragments (frag-set idx = ks*4+nt; wave stages idx = w*8+j).
#pragma unroll
  for (int j = 0; j < 8; ++j) {
    int idx = w * 8 + j;
    int ks = idx >> 2, nt = idx & 3;
    const __bf16* src = Tb2 + (nt * 16 + l15) * 256 + ks * 32 + lg * 8;
    GLD_LDS16(src, &Bl[idx * 512]);
  }
  __syncthreads();   // one-time; waves run free afterwards

  int mt0 = (blockIdx.x * 4 + w) * 2;                 // first of 2 m-tiles
  const float* b0 = x + ((size_t)(mt0 * 16 + l15) << 8) + 4 * lg;
  const float* b1 = b0 + 16 * 256;

  float4 L[16];                                       // in-flight tile regs
  bf16x8 a[8];                                        // converted A-frags
  f32x4 acc[4];

  // --- burst-load tile into L, pinned so all 16 issue back-to-back ---
#define LOAD_TILE(base)                                                   \
  do {                                                                    \
    __builtin_amdgcn_sched_barrier(0);                                    \
    _Pragma("unroll")                                                     \
    for (int ks = 0; ks < 8; ++ks) {                                      \
      L[2 * ks]     = *(const float4*)((base) + ks * 32);                 \
      L[2 * ks + 1] = *(const float4*)((base) + ks * 32 + 16);            \
    }                                                                     \
    __builtin_amdgcn_sched_barrier(0);                                    \
  } while (0)

#define CVT_TILE()                                                        \
  do {                                                                    \
    _Pragma("unroll")                                                     \
    for (int ks = 0; ks < 8; ++ks) {                                      \
      float4 lo = L[2 * ks], hi = L[2 * ks + 1];                          \
      bf16x8 v;                                                           \
      v[0] = to_bf16(lo.x); v[1] = to_bf16(lo.y);                         \
      v[2] = to_bf16(lo.z); v[3] = to_bf16(lo.w);                         \
      v[4] = to_bf16(hi.x); v[5] = to_bf16(hi.y);                         \
      v[6] = to_bf16(hi.z); v[7] = to_bf16(hi.w);                         \
      a[ks] = v;                                                          \
    }                                                                     \
  } while (0)

#define MFMA_TILE(bb)                                                     \
  do {                                                                    \
    _Pragma("unroll")                                                     \
    for (int nt = 0; nt < 4; ++nt) acc[nt] = (f32x4){0.f, 0.f, 0.f, 0.f}; \
    _Pragma("unroll")                                                     \
    for (int ks = 0; ks < 8; ++ks) {                                      \
      _Pragma("unroll")                                                   \
      for (int nt = 0; nt < 4; ++nt) {                                    \
        bf16x8 bv = *(const bf16x8*)&Bl[(bb) + (ks * 4 + nt) * 512 + lane * 8]; \
        acc[nt] = __builtin_amdgcn_mfma_f32_16x16x32_bf16(a[ks], bv, acc[nt], 0, 0, 0); \
      }                                                                   \
    }                                                                     \
  } while (0)

#define STORE_TILE(mt)                                                    \
  do {                                                                    \
    float* ob = out + ((size_t)(mt) * 16) * 64 + l15;                     \
    _Pragma("unroll")                                                     \
    for (int r = 0; r < 4; ++r)                                           \
      _Pragma("unroll")                                                   \
      for (int nt = 0; nt < 4; ++nt)                                      \
        ob[(4 * lg + r) * 64 + nt * 16] = acc[nt][r];                     \
  } while (0)

  unsigned bb = 0;
  asm volatile("" : "+v"(bb));   // opaque 0: stops LICM/CSE of B LDS reads

  LOAD_TILE(b0);
  // ---- tile 0 ----
  CVT_TILE();                 // waits loads(t0), frees L
  LOAD_TILE(b1);              // issue t1 burst; latency hides under MFMA(t0)
  MFMA_TILE(bb);
  STORE_TILE(mt0);
  // ---- tile 1 ----
  CVT_TILE();                 // t1 loads mostly landed already
  MFMA_TILE(bb);
  STORE_TILE(mt0 + 1);

#undef LOAD_TILE
#undef CVT_TILE
#undef MFMA_TILE
#undef STORE_TILE
}

// ---------------------------------------------------------------------------
extern "C" void kernel_launch(void* const* d_in, const int* in_sizes, int n_in,
                              void* d_out, int out_size, void* d_ws, size_t ws_size,
                              hipStream_t stream) {
  const float* x     = (const float*)d_in[0];
  const float* theta = (const float*)d_in[1];
  const float* phi   = (const float*)d_in[2];
  const float* outph = (const float*)d_in[3];
  float* out = (float*)d_out;

  char* ws = (char*)d_ws;
  bool tbl = ws_size >= (size_t)(832 * 1024);
  float4* t4 = (float4*)ws;                       // 512 KB
  float2* t2 = (float2*)(ws + 512 * 1024);        // 256 KB
  __bf16* Tb2 = (__bf16*)(ws + (tbl ? 768 * 1024 : 0));  // 32 KB frag-ordered T

  if (tbl) {
    olk_params<<<128, 256, 0, stream>>>(theta, phi, t4, t2);
    olk_build<true><<<16, 256, 0, stream>>>(theta, phi, outph, t4, t2, Tb2);
  } else {
    olk_build<false><<<16, 256, 0, stream>>>(theta, phi, outph, nullptr, nullptr, Tb2);
  }
  olk_mm<<<1024, 256, 0, stream>>>(x, Tb2, out);
}